// Round 5
// baseline (1126.657 us; speedup 1.0000x reference)
//
#include <hip/hip_runtime.h>
#include <hip/hip_bf16.h>

#define DD 4096
#define MM 4096
#define SS 2048
#define HH 32
#define HDD 128
#define NT 64  // GEMM K-tiles of 64

typedef unsigned short u16;
typedef __attribute__((ext_vector_type(8))) __bf16 bf16x8;
typedef __attribute__((ext_vector_type(4))) float f32x4;
typedef __attribute__((ext_vector_type(4))) float float4v;
typedef __attribute__((ext_vector_type(8))) unsigned short ushort8;
typedef __attribute__((ext_vector_type(4))) unsigned int uint4v;

__device__ __forceinline__ u16 f2bf(float f) {
  union { float f; unsigned u; } v; v.f = f;
  unsigned u = v.u;
  return (u16)((u + 0x7fffu + ((u >> 16) & 1u)) >> 16);
}
__device__ __forceinline__ float bf2f(u16 s) {
  union { unsigned u; float f; } v; v.u = ((unsigned)s) << 16;
  return v.f;
}
__device__ __forceinline__ f32x4 zero4() { f32x4 z = {0.f, 0.f, 0.f, 0.f}; return z; }

__device__ __forceinline__ void gl_lds16(const u16* g, u16* l) {
  __builtin_amdgcn_global_load_lds((__attribute__((address_space(1))) void*)(g),
                                   (__attribute__((address_space(3))) void*)(l), 16, 0, 0);
}

// ---------------- f32 -> bf16 convert (x) ----------------
__global__ __launch_bounds__(256) void k_cvt(const float* __restrict__ in,
                                             u16* __restrict__ out, int n8) {
  int i = blockIdx.x * blockDim.x + threadIdx.x;
  if (i >= n8) return;
  size_t o = (size_t)i * 8;
  float4v a = *(const float4v*)(in + o);
  float4v b = *(const float4v*)(in + o + 4);
  ushort8 v;
  v[0] = f2bf(a[0]); v[1] = f2bf(a[1]); v[2] = f2bf(a[2]); v[3] = f2bf(a[3]);
  v[4] = f2bf(b[0]); v[5] = f2bf(b[1]); v[6] = f2bf(b[2]); v[7] = f2bf(b[3]);
  *(ushort8*)(out + o) = v;
}

// ---------------- weight transpose + convert: out[n][k] = W[k][n] ----------------
__global__ __launch_bounds__(256) void k_wt(const float* __restrict__ W0,
                                            const float* __restrict__ W1,
                                            const float* __restrict__ W2,
                                            const float* __restrict__ W3,
                                            u16* __restrict__ out) {
  const float* W = blockIdx.z == 0 ? W0 : blockIdx.z == 1 ? W1 : blockIdx.z == 2 ? W2 : W3;
  u16* O = out + (size_t)blockIdx.z * DD * DD;
  __shared__ u16 t[64][65];
  int k0 = blockIdx.x * 64, n0 = blockIdx.y * 64;
  int tx = threadIdx.x, ty = threadIdx.y;  // (64,4)
#pragma unroll
  for (int i = 0; i < 16; ++i) {
    int kk = ty + i * 4;
    t[tx][kk] = f2bf(W[(size_t)(k0 + kk) * DD + n0 + tx]);
  }
  __syncthreads();
#pragma unroll
  for (int i = 0; i < 16; ++i) {
    int nn = ty + i * 4;
    O[(size_t)(n0 + nn) * DD + k0 + tx] = t[nn][tx];
  }
}

// ---------------- 256x256 8-phase bf16 GEMM (m201 template) ----------------
#define MFMA16(QM, QN)                                                             \
  _Pragma("unroll") for (int kk = 0; kk < 2; ++kk)                                 \
  _Pragma("unroll") for (int mi = 0; mi < 4; ++mi)                                 \
  _Pragma("unroll") for (int ni = 0; ni < 2; ++ni)                                 \
      acc[(QM)*4 + mi][(QN)*2 + ni] = __builtin_amdgcn_mfma_f32_16x16x32_bf16(     \
          af[mi][kk], bf[(QN)*2 + ni][kk], acc[(QM)*4 + mi][(QN)*2 + ni], 0, 0, 0);

#define RDA(BB, QM)                                                                \
  _Pragma("unroll") for (int mi = 0; mi < 4; ++mi)                                 \
  _Pragma("unroll") for (int kk = 0; kk < 2; ++kk)                                 \
      af[mi][kk] = *(const bf16x8*)((const char*)&L[BB][0][0] +                    \
          ((abase + ((QM)*4 + mi) * 2048 + kk * 64) ^ xsw));

#define RDB(BB, QN)                                                                \
  _Pragma("unroll") for (int ni = 0; ni < 2; ++ni)                                 \
  _Pragma("unroll") for (int kk = 0; kk < 2; ++kk)                                 \
      bf[(QN)*2 + ni][kk] = *(const bf16x8*)((const char*)&L[BB][1][0] +           \
          ((bbase + ((QN)*2 + ni) * 2048 + kk * 64) ^ xsw));

#define BAR() __builtin_amdgcn_s_barrier()
#define LGKM0() asm volatile("s_waitcnt lgkmcnt(0)" ::: "memory")
#define PRIO1() __builtin_amdgcn_s_setprio(1)
#define PRIO0() __builtin_amdgcn_s_setprio(0)

template <int MODE>
__global__ __launch_bounds__(512, 2) void k_gemm(const u16* __restrict__ A,
                                                 const u16* __restrict__ Bt,
                                                 void* __restrict__ Cout) {
  __shared__ __align__(16) u16 L[2][2][16384];
  const int tid = threadIdx.x;
  const int wid = tid >> 6, lane = tid & 63;
  const int g = lane >> 4, li = lane & 15;
  const int wr = wid >> 2, wc = wid & 3;

  const int bid = blockIdx.x;
  const int sw = ((bid & 7) << 5) | (bid >> 3);
  const int brow = (sw >> 4) * 256, bcol = (sw & 15) * 256;

  const int xsw = (li & 7) << 4;
  const int abase = (wr * 128 + li) * 128 + g * 16;
  const int bbase = (wc * 64 + li) * 128 + g * 16;

  const int sxy = ((tid >> 3) & 7) << 3;
  const int scol = ((tid * 8) ^ sxy) & 63;
  const int srow0 = tid >> 3;

  auto STAGE = [&](int gidx) {
    if (gidx >= 4 * NT) return;
    const int t = gidx >> 2, h = gidx & 3;
    const int bb2 = t & 1;
    const int mat = h >> 1;
    const int half = h & 1;
    const u16* G = mat ? Bt : A;
    const int rowbase = (mat ? bcol : brow) + half * 128;
    const int k0 = t << 6;
    u16* Ld = &L[bb2][mat][half * 8192 + wid * 512];
    const u16* gsrc = G + (size_t)(rowbase + srow0) * DD + k0 + scol;
    gl_lds16(gsrc, Ld);
    gl_lds16(gsrc + (size_t)64 * DD, Ld + 4096);
  };

  f32x4 acc[8][4];
#pragma unroll
  for (int m = 0; m < 8; ++m)
#pragma unroll
    for (int n = 0; n < 4; ++n) acc[m][n] = zero4();

  bf16x8 af[4][2], bf[4][2];

#pragma unroll
  for (int gi = 0; gi < 5; ++gi) STAGE(gi);
  asm volatile("s_waitcnt vmcnt(2)" ::: "memory");
  BAR();

  for (int kt = 0; kt < NT; ++kt) {
    const int bb = kt & 1;
    const int gb = 4 * kt;
    RDA(bb, 0); RDB(bb, 0);
    STAGE(gb + 5);
    BAR(); LGKM0();
    PRIO1(); MFMA16(0, 0); PRIO0();
    BAR();
    RDB(bb, 1);
    STAGE(gb + 6);
    BAR(); LGKM0();
    PRIO1(); MFMA16(0, 1); PRIO0();
    BAR();
    RDA(bb, 1);
    STAGE(gb + 7);
    BAR(); LGKM0();
    PRIO1(); MFMA16(1, 0); PRIO0();
    BAR();
    STAGE(gb + 8);
    if (kt < NT - 2) {
      asm volatile("s_waitcnt vmcnt(2)" ::: "memory");
    } else {
      asm volatile("s_waitcnt vmcnt(0)" ::: "memory");
    }
    BAR(); LGKM0();
    PRIO1(); MFMA16(1, 1); PRIO0();
    BAR();
  }

#pragma unroll
  for (int m = 0; m < 8; ++m) {
#pragma unroll
    for (int n = 0; n < 4; ++n) {
#pragma unroll
      for (int r = 0; r < 4; ++r) {
        int row = brow + wr * 128 + m * 16 + g * 4 + r;
        int col = bcol + wc * 64 + n * 16 + li;
        float v = acc[m][n][r];
        if (MODE == 0) {
          ((u16*)Cout)[(size_t)row * DD + col] = f2bf(v);
        } else if (MODE == 1) {
          ((u16*)Cout)[((size_t)((row >> 11) << 12) + col) * SS + (row & 2047)] = f2bf(v);
        } else {
          ((float*)Cout)[(size_t)row * DD + col] = v;
        }
      }
    }
  }
}

// ---------------- RoPE in-place on Q and K; Q pre-scaled by 1/sqrt(HD)*log2e ----------------
__global__ __launch_bounds__(256) void k_rope(u16* __restrict__ Q, u16* __restrict__ Kp,
                                              const float* __restrict__ fc,
                                              const float* __restrict__ fs) {
  int idx = blockIdx.x * blockDim.x + threadIdx.x;
  const int n8 = MM * DD / 8;
  const float qsc = idx < n8 ? 0.08838834764831845f * 1.44269504088896340f : 1.0f;
  u16* T = idx < n8 ? Q : Kp;
  int i = idx < n8 ? idx : idx - n8;
  int m = i >> 9;
  int c = (i & 511) * 8;
  int s = m & (SS - 1);
  int i0 = (c & (HDD - 1)) >> 1;
  size_t o = (size_t)m * DD + c;
  ushort8 v = *(ushort8*)(T + o);
  float4v cs = *(const float4v*)(fc + s * 64 + i0);
  float4v sn = *(const float4v*)(fs + s * 64 + i0);
  ushort8 ov;
#pragma unroll
  for (int p = 0; p < 4; ++p) {
    float a = bf2f(v[2 * p]), cc = bf2f(v[2 * p + 1]);
    ov[2 * p]     = f2bf((a * cs[p] - cc * sn[p]) * qsc);
    ov[2 * p + 1] = f2bf((a * sn[p] + cc * cs[p]) * qsc);
  }
  *(ushort8*)(T + o) = ov;
}

// ---------------- flash attention v4: no K/V staging, no in-loop barriers ----------------
// K/V fragments load global->reg directly (L2/L3-resident); swapped QK^T keeps
// softmax lane-parallel; mask only on diagonal tile; T13 defer-rescale (THR=8).
__global__ __launch_bounds__(256) void k_attn(const u16* __restrict__ Q,
                                              const u16* __restrict__ K,
                                              const u16* __restrict__ VT,
                                              u16* __restrict__ O) {
  __shared__ __align__(16) u16 Pl[4][16 * 64];
  const int bh = blockIdx.x;       // fast dim -> all qt-blocks of a (b,h) on XCD bh%8
  const int qt = 31 - blockIdx.y;  // heavy blocks dispatch first
  const int b = bh >> 5, h = bh & 31;
  const int tid = threadIdx.x, w = tid >> 6, lane = tid & 63;
  const int g = lane >> 4, li = lane & 15;

  // per-lane fragment base pointers (k-contiguous 16B loads)
  const u16* Qbase = Q + ((size_t)(b * SS + qt * 64 + w * 16 + li)) * DD + h * HDD;
  const u16* Kbase = K + ((size_t)(b * SS + li)) * DD + h * HDD + g * 8;
  const u16* Vbase = VT + ((size_t)(bh * HDD + li)) * SS + g * 8;

  bf16x8 qf[4];
#pragma unroll
  for (int ks = 0; ks < 4; ++ks)
    qf[ks] = *(const bf16x8*)(Qbase + ks * 32 + g * 8);

  f32x4 oa[8];
#pragma unroll
  for (int f = 0; f < 8; ++f) oa[f] = zero4();
  float mrun = -1e30f, lrun = 0.f;  // scalar state for q-row = w*16 + li

  const int wli = w * 16 + li;

  auto tile = [&](int kt, bool diag) {
    const u16* Kt = Kbase + (size_t)(kt * 64) * DD;
    const u16* Vt = Vbase + kt * 64;

    // swapped QK^T: sc[ktg][r] = S[k = kt*64 + ktg*16 + g*4 + r][q = wli]
    f32x4 sc[4];
#pragma unroll
    for (int ktg = 0; ktg < 4; ++ktg) sc[ktg] = zero4();
    PRIO1();
#pragma unroll
    for (int ks = 0; ks < 4; ++ks) {
#pragma unroll
      for (int ktg = 0; ktg < 4; ++ktg) {
        bf16x8 kf = *(const bf16x8*)(Kt + (size_t)(ktg * 16) * DD + ks * 32);
        sc[ktg] = __builtin_amdgcn_mfma_f32_16x16x32_bf16(kf, qf[ks], sc[ktg], 0, 0, 0);
      }
    }
    PRIO0();

    // lane-parallel online softmax (Q pre-scaled: sc already in log2 domain)
    float p[16];
    float tmax = -1e30f;
#pragma unroll
    for (int ktg = 0; ktg < 4; ++ktg) {
#pragma unroll
      for (int r = 0; r < 4; ++r) {
        float s = sc[ktg][r];
        if (diag && (ktg * 16 + g * 4 + r > wli)) s = -1e30f;
        p[ktg * 4 + r] = s;
        tmax = fmaxf(tmax, s);
      }
    }
    tmax = fmaxf(tmax, __shfl_xor(tmax, 16));
    tmax = fmaxf(tmax, __shfl_xor(tmax, 32));

    if (__all(tmax <= mrun + 8.f)) {
      // T13 defer: keep old max, skip rescale (p bounded by 2^8)
      float su = 0.f;
#pragma unroll
      for (int i = 0; i < 16; ++i) {
        p[i] = exp2f(p[i] - mrun);
        su += p[i];
      }
      su += __shfl_xor(su, 16);
      su += __shfl_xor(su, 32);
      lrun += su;
    } else {
      float mnew = fmaxf(mrun, tmax);
      float alpha = exp2f(mrun - mnew);
      mrun = mnew;
      float su = 0.f;
#pragma unroll
      for (int i = 0; i < 16; ++i) {
        p[i] = exp2f(p[i] - mnew);
        su += p[i];
      }
      su += __shfl_xor(su, 16);
      su += __shfl_xor(su, 32);
      lrun = lrun * alpha + su;
      float av[4];
#pragma unroll
      for (int r = 0; r < 4; ++r) av[r] = __shfl(alpha, g * 20 + r);
#pragma unroll
      for (int f = 0; f < 8; ++f)
#pragma unroll
        for (int r = 0; r < 4; ++r) oa[f][r] *= av[r];
    }

    // P -> LDS (per-wave region; packed pairs, 2-way conflict = free)
    {
      char* Pb = (char*)Pl[w];
      const int swz = (li & 7) << 4;
#pragma unroll
      for (int ktg = 0; ktg < 4; ++ktg) {
#pragma unroll
        for (int j = 0; j < 2; ++j) {
          unsigned pk = (unsigned)f2bf(p[ktg * 4 + 2 * j]) |
                        ((unsigned)f2bf(p[ktg * 4 + 2 * j + 1]) << 16);
          int off = (li * 128 + (ktg * 16 + g * 4 + 2 * j) * 2) ^ swz;
          *(unsigned*)(Pb + off) = pk;
        }
      }
    }
    asm volatile("s_waitcnt lgkmcnt(0)" ::: "memory");

    // PV: O[16q][128d] += P[16q][64k] * V[64k][128d]  (V frags direct from global)
    PRIO1();
#pragma unroll
    for (int ks2 = 0; ks2 < 2; ++ks2) {
      int poff = (li * 128 + (ks2 * 32 + g * 8) * 2) ^ ((li & 7) << 4);
      bf16x8 pfrag = *(const bf16x8*)((const char*)Pl[w] + poff);
#pragma unroll
      for (int f = 0; f < 8; ++f) {
        bf16x8 vf = *(const bf16x8*)(Vt + (size_t)(f * 16) * SS + ks2 * 32);
        oa[f] = __builtin_amdgcn_mfma_f32_16x16x32_bf16(pfrag, vf, oa[f], 0, 0, 0);
      }
    }
    PRIO0();
  };

  for (int kt = 0; kt < qt; ++kt) tile(kt, false);
  tile(qt, true);

  // epilogue: O rows q = g*4 + r; fetch l from the lane owning that q
  float lv[4];
#pragma unroll
  for (int r = 0; r < 4; ++r) lv[r] = __shfl(lrun, g * 20 + r);
  u16* Ob = O + ((size_t)(b * SS + qt * 64 + w * 16 + g * 4)) * DD + h * HDD;
#pragma unroll
  for (int r = 0; r < 4; ++r) {
    float inv = 1.f / lv[r];
#pragma unroll
    for (int f = 0; f < 8; ++f)
      Ob[(size_t)r * DD + f * 16 + li] = f2bf(oa[f][r] * inv);
  }
}

// ---------------- host ----------------
extern "C" void kernel_launch(void* const* d_in, const int* in_sizes, int n_in,
                              void* d_out, int out_size, void* d_ws, size_t ws_size,
                              hipStream_t stream) {
  (void)in_sizes; (void)n_in; (void)out_size; (void)ws_size;
  const float* x    = (const float*)d_in[0];
  const float* Wq   = (const float*)d_in[1];
  const float* Wk   = (const float*)d_in[2];
  const float* Wv   = (const float*)d_in[3];
  const float* Wo   = (const float*)d_in[4];
  const float* fcos = (const float*)d_in[5];
  const float* fsin = (const float*)d_in[6];

  u16* ws = (u16*)d_ws;
  const size_t MAT = (size_t)4096 * 4096;
  u16* xb    = ws + 0 * MAT;
  u16* wqt   = ws + 1 * MAT;
  u16* wkt   = ws + 2 * MAT;
  u16* wvt   = ws + 3 * MAT;
  u16* wot   = ws + 4 * MAT;
  u16* Qb    = ws + 5 * MAT;
  u16* Kb    = ws + 6 * MAT;
  u16* VTb   = ws + 7 * MAT;
  u16* attnb = ws + 8 * MAT;

  k_cvt<<<dim3(8192), dim3(256), 0, stream>>>(x, xb, (int)(MAT / 8));
  k_wt<<<dim3(64, 64, 4), dim3(64, 4), 0, stream>>>(Wq, Wk, Wv, Wo, wqt);
  k_gemm<0><<<dim3(256), dim3(512), 0, stream>>>(xb, wqt, (void*)Qb);
  k_gemm<0><<<dim3(256), dim3(512), 0, stream>>>(xb, wkt, (void*)Kb);
  k_gemm<1><<<dim3(256), dim3(512), 0, stream>>>(xb, wvt, (void*)VTb);
  k_rope<<<dim3(16384), dim3(256), 0, stream>>>(Qb, Kb, fcos, fsin);
  k_attn<<<dim3(64, 32), dim3(256), 0, stream>>>(Qb, Kb, VTb, attnb);
  k_gemm<2><<<dim3(256), dim3(512), 0, stream>>>(attnb, wot, d_out);
}

// Round 6
// 864.331 us; speedup vs baseline: 1.3035x; 1.3035x over previous
//
#include <hip/hip_runtime.h>
#include <hip/hip_bf16.h>

#define DD 4096
#define MM 4096
#define SS 2048
#define HH 32
#define HDD 128
#define NT 64  // GEMM K-tiles of 64

typedef unsigned short u16;
typedef __attribute__((ext_vector_type(8))) __bf16 bf16x8;
typedef __attribute__((ext_vector_type(4))) float f32x4;
typedef __attribute__((ext_vector_type(4))) float float4v;
typedef __attribute__((ext_vector_type(8))) unsigned short ushort8;
typedef __attribute__((ext_vector_type(4))) unsigned int uint4v;

__device__ __forceinline__ u16 f2bf(float f) {
  union { float f; unsigned u; } v; v.f = f;
  unsigned u = v.u;
  return (u16)((u + 0x7fffu + ((u >> 16) & 1u)) >> 16);
}
__device__ __forceinline__ float bf2f(u16 s) {
  union { unsigned u; float f; } v; v.u = ((unsigned)s) << 16;
  return v.f;
}
__device__ __forceinline__ f32x4 zero4() { f32x4 z = {0.f, 0.f, 0.f, 0.f}; return z; }

__device__ __forceinline__ void gl_lds16(const u16* g, u16* l) {
  __builtin_amdgcn_global_load_lds((__attribute__((address_space(1))) void*)(g),
                                   (__attribute__((address_space(3))) void*)(l), 16, 0, 0);
}

// ---------------- f32 -> bf16 convert (x) ----------------
__global__ __launch_bounds__(256) void k_cvt(const float* __restrict__ in,
                                             u16* __restrict__ out, int n8) {
  int i = blockIdx.x * blockDim.x + threadIdx.x;
  if (i >= n8) return;
  size_t o = (size_t)i * 8;
  float4v a = *(const float4v*)(in + o);
  float4v b = *(const float4v*)(in + o + 4);
  ushort8 v;
  v[0] = f2bf(a[0]); v[1] = f2bf(a[1]); v[2] = f2bf(a[2]); v[3] = f2bf(a[3]);
  v[4] = f2bf(b[0]); v[5] = f2bf(b[1]); v[6] = f2bf(b[2]); v[7] = f2bf(b[3]);
  *(ushort8*)(out + o) = v;
}

// ---------------- weight transpose + convert: out[n][k] = W[k][n] ----------------
__global__ __launch_bounds__(256) void k_wt(const float* __restrict__ W0,
                                            const float* __restrict__ W1,
                                            const float* __restrict__ W2,
                                            const float* __restrict__ W3,
                                            u16* __restrict__ out) {
  const float* W = blockIdx.z == 0 ? W0 : blockIdx.z == 1 ? W1 : blockIdx.z == 2 ? W2 : W3;
  u16* O = out + (size_t)blockIdx.z * DD * DD;
  __shared__ u16 t[64][65];
  int k0 = blockIdx.x * 64, n0 = blockIdx.y * 64;
  int tx = threadIdx.x, ty = threadIdx.y;  // (64,4)
#pragma unroll
  for (int i = 0; i < 16; ++i) {
    int kk = ty + i * 4;
    t[tx][kk] = f2bf(W[(size_t)(k0 + kk) * DD + n0 + tx]);
  }
  __syncthreads();
#pragma unroll
  for (int i = 0; i < 16; ++i) {
    int nn = ty + i * 4;
    O[(size_t)(n0 + nn) * DD + k0 + tx] = t[nn][tx];
  }
}

// ---------------- 256x256 8-phase bf16 GEMM (m201 template) ----------------
#define MFMA16(QM, QN)                                                             \
  _Pragma("unroll") for (int kk = 0; kk < 2; ++kk)                                 \
  _Pragma("unroll") for (int mi = 0; mi < 4; ++mi)                                 \
  _Pragma("unroll") for (int ni = 0; ni < 2; ++ni)                                 \
      acc[(QM)*4 + mi][(QN)*2 + ni] = __builtin_amdgcn_mfma_f32_16x16x32_bf16(     \
          af[mi][kk], bf[(QN)*2 + ni][kk], acc[(QM)*4 + mi][(QN)*2 + ni], 0, 0, 0);

#define RDA(BB, QM)                                                                \
  _Pragma("unroll") for (int mi = 0; mi < 4; ++mi)                                 \
  _Pragma("unroll") for (int kk = 0; kk < 2; ++kk)                                 \
      af[mi][kk] = *(const bf16x8*)((const char*)&L[BB][0][0] +                    \
          ((abase + ((QM)*4 + mi) * 2048 + kk * 64) ^ xsw));

#define RDB(BB, QN)                                                                \
  _Pragma("unroll") for (int ni = 0; ni < 2; ++ni)                                 \
  _Pragma("unroll") for (int kk = 0; kk < 2; ++kk)                                 \
      bf[(QN)*2 + ni][kk] = *(const bf16x8*)((const char*)&L[BB][1][0] +           \
          ((bbase + ((QN)*2 + ni) * 2048 + kk * 64) ^ xsw));

#define BAR() __builtin_amdgcn_s_barrier()
#define LGKM0() asm volatile("s_waitcnt lgkmcnt(0)" ::: "memory")
#define PRIO1() __builtin_amdgcn_s_setprio(1)
#define PRIO0() __builtin_amdgcn_s_setprio(0)

template <int MODE>
__global__ __launch_bounds__(512, 2) void k_gemm(const u16* __restrict__ A,
                                                 const u16* __restrict__ Bt,
                                                 void* __restrict__ Cout) {
  __shared__ __align__(16) u16 L[2][2][16384];
  const int tid = threadIdx.x;
  const int wid = tid >> 6, lane = tid & 63;
  const int g = lane >> 4, li = lane & 15;
  const int wr = wid >> 2, wc = wid & 3;

  const int bid = blockIdx.x;
  const int sw = ((bid & 7) << 5) | (bid >> 3);
  const int brow = (sw >> 4) * 256, bcol = (sw & 15) * 256;

  const int xsw = (li & 7) << 4;
  const int abase = (wr * 128 + li) * 128 + g * 16;
  const int bbase = (wc * 64 + li) * 128 + g * 16;

  const int sxy = ((tid >> 3) & 7) << 3;
  const int scol = ((tid * 8) ^ sxy) & 63;
  const int srow0 = tid >> 3;

  auto STAGE = [&](int gidx) {
    if (gidx >= 4 * NT) return;
    const int t = gidx >> 2, h = gidx & 3;
    const int bb2 = t & 1;
    const int mat = h >> 1;
    const int half = h & 1;
    const u16* G = mat ? Bt : A;
    const int rowbase = (mat ? bcol : brow) + half * 128;
    const int k0 = t << 6;
    u16* Ld = &L[bb2][mat][half * 8192 + wid * 512];
    const u16* gsrc = G + (size_t)(rowbase + srow0) * DD + k0 + scol;
    gl_lds16(gsrc, Ld);
    gl_lds16(gsrc + (size_t)64 * DD, Ld + 4096);
  };

  f32x4 acc[8][4];
#pragma unroll
  for (int m = 0; m < 8; ++m)
#pragma unroll
    for (int n = 0; n < 4; ++n) acc[m][n] = zero4();

  bf16x8 af[4][2], bf[4][2];

#pragma unroll
  for (int gi = 0; gi < 5; ++gi) STAGE(gi);
  asm volatile("s_waitcnt vmcnt(2)" ::: "memory");
  BAR();

  for (int kt = 0; kt < NT; ++kt) {
    const int bb = kt & 1;
    const int gb = 4 * kt;
    RDA(bb, 0); RDB(bb, 0);
    STAGE(gb + 5);
    BAR(); LGKM0();
    PRIO1(); MFMA16(0, 0); PRIO0();
    BAR();
    RDB(bb, 1);
    STAGE(gb + 6);
    BAR(); LGKM0();
    PRIO1(); MFMA16(0, 1); PRIO0();
    BAR();
    RDA(bb, 1);
    STAGE(gb + 7);
    BAR(); LGKM0();
    PRIO1(); MFMA16(1, 0); PRIO0();
    BAR();
    STAGE(gb + 8);
    if (kt < NT - 2) {
      asm volatile("s_waitcnt vmcnt(2)" ::: "memory");
    } else {
      asm volatile("s_waitcnt vmcnt(0)" ::: "memory");
    }
    BAR(); LGKM0();
    PRIO1(); MFMA16(1, 1); PRIO0();
    BAR();
  }

#pragma unroll
  for (int m = 0; m < 8; ++m) {
#pragma unroll
    for (int n = 0; n < 4; ++n) {
#pragma unroll
      for (int r = 0; r < 4; ++r) {
        int row = brow + wr * 128 + m * 16 + g * 4 + r;
        int col = bcol + wc * 64 + n * 16 + li;
        float v = acc[m][n][r];
        if (MODE == 0) {
          ((u16*)Cout)[(size_t)row * DD + col] = f2bf(v);
        } else if (MODE == 1) {
          ((u16*)Cout)[((size_t)((row >> 11) << 12) + col) * SS + (row & 2047)] = f2bf(v);
        } else {
          ((float*)Cout)[(size_t)row * DD + col] = v;
        }
      }
    }
  }
}

// ---------------- RoPE in-place on Q and K; Q pre-scaled by 1/sqrt(HD)*log2e ----------------
__global__ __launch_bounds__(256) void k_rope(u16* __restrict__ Q, u16* __restrict__ Kp,
                                              const float* __restrict__ fc,
                                              const float* __restrict__ fs) {
  int idx = blockIdx.x * blockDim.x + threadIdx.x;
  const int n8 = MM * DD / 8;
  const float qsc = idx < n8 ? 0.08838834764831845f * 1.44269504088896340f : 1.0f;
  u16* T = idx < n8 ? Q : Kp;
  int i = idx < n8 ? idx : idx - n8;
  int m = i >> 9;
  int c = (i & 511) * 8;
  int s = m & (SS - 1);
  int i0 = (c & (HDD - 1)) >> 1;
  size_t o = (size_t)m * DD + c;
  ushort8 v = *(ushort8*)(T + o);
  float4v cs = *(const float4v*)(fc + s * 64 + i0);
  float4v sn = *(const float4v*)(fs + s * 64 + i0);
  ushort8 ov;
#pragma unroll
  for (int p = 0; p < 4; ++p) {
    float a = bf2f(v[2 * p]), cc = bf2f(v[2 * p + 1]);
    ov[2 * p]     = f2bf((a * cs[p] - cc * sn[p]) * qsc);
    ov[2 * p + 1] = f2bf((a * sn[p] + cc * cs[p]) * qsc);
  }
  *(ushort8*)(T + o) = ov;
}

// ---------------- flash attention v6: KVBLK=32, dbuf via global_load_lds, 2-phase pipeline ----------------
// LDS 36KB -> 4 blocks/CU. STAGE(kt+1) issued before compute(kt); one vmcnt(0)+barrier per tile.
// Swizzles: K granule XOR ((row&7)<<4) [within-row]; V/P granule XOR (((row>>1)&7)<<4)
// [cross-row, mask depends only on un-XORed bits -> bijective]; DMA dest linear,
// source inverse-swizzled (rule 21).
__global__ __launch_bounds__(256) void k_attn(const u16* __restrict__ Q,
                                              const u16* __restrict__ K,
                                              const u16* __restrict__ VT,
                                              u16* __restrict__ O) {
  __shared__ __align__(16) u16 Kl[2][32 * 128];
  __shared__ __align__(16) u16 Vl[2][128 * 32];
  __shared__ __align__(16) u16 Pl[4][16 * 32];
  const int bh = blockIdx.x;       // fast dim -> all qt-blocks of (b,h) on XCD bh%8
  const int qt = 31 - blockIdx.y;  // heavy blocks dispatch first
  const int b = bh >> 5, h = bh & 31;
  const int tid = threadIdx.x, w = tid >> 6, lane = tid & 63;
  const int g = lane >> 4, li = lane & 15;

  const u16* Qbase = Q + ((size_t)(b * SS + qt * 64 + w * 16 + li)) * DD + h * HDD;
  const u16* Kbase = K + ((size_t)(b * SS)) * DD + h * HDD;
  const u16* Vbase = VT + ((size_t)bh) * HDD * SS;

  bf16x8 qf[4];
#pragma unroll
  for (int ks = 0; ks < 4; ++ks)
    qf[ks] = *(const bf16x8*)(Qbase + ks * 32 + g * 8);

  f32x4 oa[8];
#pragma unroll
  for (int f = 0; f < 8; ++f) oa[f] = zero4();
  float mrun = -1e30f, lrun = 0.f;  // scalar state for q-row = w*16 + li
  const int wli = w * 16 + li;

  // --- staging address precompute (per-lane global sources, wave-uniform LDS dests) ---
  // K: call c (0,1): lane writes LDS row (w*8 + c*4 + lane>>4), granule lane&15.
  //    logical src granule = (lane&15) ^ (c*4 + lane>>4).
  const int krow0 = w * 8 + (lane >> 4);          // + c*4
  const int ksg0 = (lane & 15) ^ (lane >> 4);     // c=0
  const int ksg1 = (lane & 15) ^ (4 + (lane >> 4));
  // V: call c: dr_phys = c*64 + w*16 + lane>>2, pg = lane&3;
  //    a_log = (dr_phys*64 + pg*16) ^ (((dr_phys>>1)&7)<<4) -> dr_log, kgran.
  const int vdr0 = w * 16 + (lane >> 2);  // c=0 ; c=1 adds 64
  const int va0 = (vdr0 * 64 + (lane & 3) * 16) ^ (((vdr0 >> 1) & 7) << 4);
  const int vdr1 = vdr0 + 64;
  const int va1 = (vdr1 * 64 + (lane & 3) * 16) ^ (((vdr1 >> 1) & 7) << 4);

  auto STAGE = [&](int t, int nb) {
    const u16* Kt = Kbase + (size_t)(t * 32) * DD;
    gl_lds16(Kt + (size_t)krow0 * DD + ksg0 * 8, &Kl[nb][(w * 8) * 128]);
    gl_lds16(Kt + (size_t)(krow0 + 4) * DD + ksg1 * 8, &Kl[nb][(w * 8 + 4) * 128]);
    const u16* Vt = Vbase + t * 32;
    gl_lds16(Vt + (size_t)(va0 >> 6) * SS + ((va0 >> 4) & 3) * 8, &Vl[nb][w * 512]);
    gl_lds16(Vt + (size_t)(va1 >> 6) * SS + ((va1 >> 4) & 3) * 8, &Vl[nb][2048 + w * 512]);
  };

  const int ktmax = 2 * qt + 1;
  STAGE(0, 0);
  asm volatile("s_waitcnt vmcnt(0)" ::: "memory");
  __syncthreads();

  for (int kt = 0; kt <= ktmax; ++kt) {
    const int cb = kt & 1;
    if (kt < ktmax) STAGE(kt + 1, cb ^ 1);

    // QK^T (swapped): sc[ktg][r] = S[k = kt*32 + ktg*16 + g*4 + r][q = wli]
    f32x4 sc[2];
    sc[0] = zero4(); sc[1] = zero4();
    PRIO1();
#pragma unroll
    for (int ks = 0; ks < 4; ++ks) {
#pragma unroll
      for (int ktg = 0; ktg < 2; ++ktg) {
        int kr = ktg * 16 + li;
        int off = (kr * 256 + (ks * 32 + g * 8) * 2) ^ ((kr & 7) << 4);
        bf16x8 kf = *(const bf16x8*)((const char*)Kl[cb] + off);
        sc[ktg] = __builtin_amdgcn_mfma_f32_16x16x32_bf16(kf, qf[ks], sc[ktg], 0, 0, 0);
      }
    }
    PRIO0();

    // lane-parallel online softmax (Q pre-scaled into log2 domain)
    const int koff = kt * 32 - qt * 64;  // >=0 only on the two diagonal tiles
    float p[8];
    float tmax = -1e30f;
#pragma unroll
    for (int ktg = 0; ktg < 2; ++ktg) {
#pragma unroll
      for (int r = 0; r < 4; ++r) {
        float s = sc[ktg][r];
        if (koff >= 0 && (koff + ktg * 16 + g * 4 + r > wli)) s = -1e30f;
        p[ktg * 4 + r] = s;
        tmax = fmaxf(tmax, s);
      }
    }
    tmax = fmaxf(tmax, __shfl_xor(tmax, 16));
    tmax = fmaxf(tmax, __shfl_xor(tmax, 32));

    if (__all(tmax <= mrun + 8.f)) {  // T13 defer-max
      float su = 0.f;
#pragma unroll
      for (int i = 0; i < 8; ++i) { p[i] = exp2f(p[i] - mrun); su += p[i]; }
      su += __shfl_xor(su, 16);
      su += __shfl_xor(su, 32);
      lrun += su;
    } else {
      float mnew = fmaxf(mrun, tmax);
      float alpha = exp2f(mrun - mnew);
      mrun = mnew;
      float su = 0.f;
#pragma unroll
      for (int i = 0; i < 8; ++i) { p[i] = exp2f(p[i] - mnew); su += p[i]; }
      su += __shfl_xor(su, 16);
      su += __shfl_xor(su, 32);
      lrun = lrun * alpha + su;
      float av[4];
#pragma unroll
      for (int r = 0; r < 4; ++r) av[r] = __shfl(alpha, g * 20 + r);
#pragma unroll
      for (int f = 0; f < 8; ++f)
#pragma unroll
        for (int r = 0; r < 4; ++r) oa[f][r] *= av[r];
    }

    // P -> LDS (per-wave region; row q=li of [16][32], V-style cross-row swizzle)
    {
      char* Pb = (char*)Pl[w];
      const int swz = ((li >> 1) & 7) << 4;
#pragma unroll
      for (int ktg = 0; ktg < 2; ++ktg) {
#pragma unroll
        for (int j = 0; j < 2; ++j) {
          unsigned pk = (unsigned)f2bf(p[ktg * 4 + 2 * j]) |
                        ((unsigned)f2bf(p[ktg * 4 + 2 * j + 1]) << 16);
          int off = (li * 64 + ktg * 32 + g * 8 + 4 * j) ^ swz;
          *(unsigned*)(Pb + off) = pk;
        }
      }
    }
    asm volatile("s_waitcnt lgkmcnt(0)" ::: "memory");

    // PV: O[16q][128d] += P[16q][32k] * V[32k][128d]
    PRIO1();
    {
      int poff = (li * 64 + g * 16) ^ (((li >> 1) & 7) << 4);
      bf16x8 pfrag = *(const bf16x8*)((const char*)Pl[w] + poff);
#pragma unroll
      for (int f = 0; f < 8; ++f) {
        int dr = f * 16 + li;
        int voff = (dr * 64 + g * 16) ^ (((dr >> 1) & 7) << 4);
        bf16x8 vf = *(const bf16x8*)((const char*)Vl[cb] + voff);
        oa[f] = __builtin_amdgcn_mfma_f32_16x16x32_bf16(pfrag, vf, oa[f], 0, 0, 0);
      }
    }
    PRIO0();

    asm volatile("s_waitcnt vmcnt(0)" ::: "memory");  // next tile's DMA landed
    __syncthreads();                                  // all waves done with buf cb
  }

  // epilogue: O rows q = g*4 + r; fetch l from the lane owning that q
  float lv[4];
#pragma unroll
  for (int r = 0; r < 4; ++r) lv[r] = __shfl(lrun, g * 20 + r);
  u16* Ob = O + ((size_t)(b * SS + qt * 64 + w * 16 + g * 4)) * DD + h * HDD;
#pragma unroll
  for (int r = 0; r < 4; ++r) {
    float inv = 1.f / lv[r];
#pragma unroll
    for (int f = 0; f < 8; ++f)
      Ob[(size_t)r * DD + f * 16 + li] = f2bf(oa[f][r] * inv);
  }
}

// ---------------- host ----------------
extern "C" void kernel_launch(void* const* d_in, const int* in_sizes, int n_in,
                              void* d_out, int out_size, void* d_ws, size_t ws_size,
                              hipStream_t stream) {
  (void)in_sizes; (void)n_in; (void)out_size; (void)ws_size;
  const float* x    = (const float*)d_in[0];
  const float* Wq   = (const float*)d_in[1];
  const float* Wk   = (const float*)d_in[2];
  const float* Wv   = (const float*)d_in[3];
  const float* Wo   = (const float*)d_in[4];
  const float* fcos = (const float*)d_in[5];
  const float* fsin = (const float*)d_in[6];

  u16* ws = (u16*)d_ws;
  const size_t MAT = (size_t)4096 * 4096;
  u16* xb    = ws + 0 * MAT;
  u16* wqt   = ws + 1 * MAT;
  u16* wkt   = ws + 2 * MAT;
  u16* wvt   = ws + 3 * MAT;
  u16* wot   = ws + 4 * MAT;
  u16* Qb    = ws + 5 * MAT;
  u16* Kb    = ws + 6 * MAT;
  u16* VTb   = ws + 7 * MAT;
  u16* attnb = ws + 8 * MAT;

  k_cvt<<<dim3(8192), dim3(256), 0, stream>>>(x, xb, (int)(MAT / 8));
  k_wt<<<dim3(64, 64, 4), dim3(64, 4), 0, stream>>>(Wq, Wk, Wv, Wo, wqt);
  k_gemm<0><<<dim3(256), dim3(512), 0, stream>>>(xb, wqt, (void*)Qb);
  k_gemm<0><<<dim3(256), dim3(512), 0, stream>>>(xb, wkt, (void*)Kb);
  k_gemm<1><<<dim3(256), dim3(512), 0, stream>>>(xb, wvt, (void*)VTb);
  k_rope<<<dim3(16384), dim3(256), 0, stream>>>(Qb, Kb, fcos, fsin);
  k_attn<<<dim3(64, 32), dim3(256), 0, stream>>>(Qb, Kb, VTb, attnb);
  k_gemm<2><<<dim3(256), dim3(512), 0, stream>>>(attnb, wot, d_out);
}

// Round 7
// 812.840 us; speedup vs baseline: 1.3861x; 1.0633x over previous
//
#include <hip/hip_runtime.h>
#include <hip/hip_bf16.h>

#define DD 4096
#define MM 4096
#define SS 2048
#define HH 32
#define HDD 128
#define NT 64  // GEMM K-tiles of 64

typedef unsigned short u16;
typedef __attribute__((ext_vector_type(8))) __bf16 bf16x8;
typedef __attribute__((ext_vector_type(4))) float f32x4;
typedef __attribute__((ext_vector_type(4))) float float4v;
typedef __attribute__((ext_vector_type(8))) unsigned short ushort8;
typedef __attribute__((ext_vector_type(4))) unsigned int uint4v;

__device__ __forceinline__ u16 f2bf(float f) {
  union { float f; unsigned u; } v; v.f = f;
  unsigned u = v.u;
  return (u16)((u + 0x7fffu + ((u >> 16) & 1u)) >> 16);
}
__device__ __forceinline__ float bf2f(u16 s) {
  union { unsigned u; float f; } v; v.u = ((unsigned)s) << 16;
  return v.f;
}
__device__ __forceinline__ f32x4 zero4() { f32x4 z = {0.f, 0.f, 0.f, 0.f}; return z; }

__device__ __forceinline__ void gl_lds16(const u16* g, u16* l) {
  __builtin_amdgcn_global_load_lds((__attribute__((address_space(1))) void*)(g),
                                   (__attribute__((address_space(3))) void*)(l), 16, 0, 0);
}

// packed f32x2 -> bf16x2 (1 instr; RNE on gfx950)
__device__ __forceinline__ unsigned cvtpk(float lo, float hi) {
  unsigned r;
  asm("v_cvt_pk_bf16_f32 %0, %1, %2" : "=v"(r) : "v"(lo), "v"(hi));
  return r;
}
// raw hardware exp2 (domain-safe here: args <= 0, -1e30 -> 0)
__device__ __forceinline__ float exp2a(float x) {
  float r;
  asm("v_exp_f32 %0, %1" : "=v"(r) : "v"(x));
  return r;
}

// ---------------- f32 -> bf16 convert (x) ----------------
__global__ __launch_bounds__(256) void k_cvt(const float* __restrict__ in,
                                             u16* __restrict__ out, int n8) {
  int i = blockIdx.x * blockDim.x + threadIdx.x;
  if (i >= n8) return;
  size_t o = (size_t)i * 8;
  float4v a = *(const float4v*)(in + o);
  float4v b = *(const float4v*)(in + o + 4);
  ushort8 v;
  v[0] = f2bf(a[0]); v[1] = f2bf(a[1]); v[2] = f2bf(a[2]); v[3] = f2bf(a[3]);
  v[4] = f2bf(b[0]); v[5] = f2bf(b[1]); v[6] = f2bf(b[2]); v[7] = f2bf(b[3]);
  *(ushort8*)(out + o) = v;
}

// ---------------- weight transpose + convert: out[n][k] = W[k][n] ----------------
__global__ __launch_bounds__(256) void k_wt(const float* __restrict__ W0,
                                            const float* __restrict__ W1,
                                            const float* __restrict__ W2,
                                            const float* __restrict__ W3,
                                            u16* __restrict__ out) {
  const float* W = blockIdx.z == 0 ? W0 : blockIdx.z == 1 ? W1 : blockIdx.z == 2 ? W2 : W3;
  u16* O = out + (size_t)blockIdx.z * DD * DD;
  __shared__ u16 t[64][65];
  int k0 = blockIdx.x * 64, n0 = blockIdx.y * 64;
  int tx = threadIdx.x, ty = threadIdx.y;  // (64,4)
#pragma unroll
  for (int i = 0; i < 16; ++i) {
    int kk = ty + i * 4;
    t[tx][kk] = f2bf(W[(size_t)(k0 + kk) * DD + n0 + tx]);
  }
  __syncthreads();
#pragma unroll
  for (int i = 0; i < 16; ++i) {
    int nn = ty + i * 4;
    O[(size_t)(n0 + nn) * DD + k0 + tx] = t[nn][tx];
  }
}

// ---------------- 256x256 8-phase bf16 GEMM (m201 template) ----------------
#define MFMA16(QM, QN)                                                             \
  _Pragma("unroll") for (int kk = 0; kk < 2; ++kk)                                 \
  _Pragma("unroll") for (int mi = 0; mi < 4; ++mi)                                 \
  _Pragma("unroll") for (int ni = 0; ni < 2; ++ni)                                 \
      acc[(QM)*4 + mi][(QN)*2 + ni] = __builtin_amdgcn_mfma_f32_16x16x32_bf16(     \
          af[mi][kk], bf[(QN)*2 + ni][kk], acc[(QM)*4 + mi][(QN)*2 + ni], 0, 0, 0);

#define RDA(BB, QM)                                                                \
  _Pragma("unroll") for (int mi = 0; mi < 4; ++mi)                                 \
  _Pragma("unroll") for (int kk = 0; kk < 2; ++kk)                                 \
      af[mi][kk] = *(const bf16x8*)((const char*)&L[BB][0][0] +                    \
          ((abase + ((QM)*4 + mi) * 2048 + kk * 64) ^ xsw));

#define RDB(BB, QN)                                                                \
  _Pragma("unroll") for (int ni = 0; ni < 2; ++ni)                                 \
  _Pragma("unroll") for (int kk = 0; kk < 2; ++kk)                                 \
      bf[(QN)*2 + ni][kk] = *(const bf16x8*)((const char*)&L[BB][1][0] +           \
          ((bbase + ((QN)*2 + ni) * 2048 + kk * 64) ^ xsw));

#define BAR() __builtin_amdgcn_s_barrier()
#define LGKM0() asm volatile("s_waitcnt lgkmcnt(0)" ::: "memory")
#define PRIO1() __builtin_amdgcn_s_setprio(1)
#define PRIO0() __builtin_amdgcn_s_setprio(0)

template <int MODE>
__global__ __launch_bounds__(512, 2) void k_gemm(const u16* __restrict__ A,
                                                 const u16* __restrict__ Bt,
                                                 void* __restrict__ Cout) {
  __shared__ __align__(16) u16 L[2][2][16384];
  const int tid = threadIdx.x;
  const int wid = tid >> 6, lane = tid & 63;
  const int g = lane >> 4, li = lane & 15;
  const int wr = wid >> 2, wc = wid & 3;

  const int bid = blockIdx.x;
  const int sw = ((bid & 7) << 5) | (bid >> 3);
  const int brow = (sw >> 4) * 256, bcol = (sw & 15) * 256;

  const int xsw = (li & 7) << 4;
  const int abase = (wr * 128 + li) * 128 + g * 16;
  const int bbase = (wc * 64 + li) * 128 + g * 16;

  const int sxy = ((tid >> 3) & 7) << 3;
  const int scol = ((tid * 8) ^ sxy) & 63;
  const int srow0 = tid >> 3;

  auto STAGE = [&](int gidx) {
    if (gidx >= 4 * NT) return;
    const int t = gidx >> 2, h = gidx & 3;
    const int bb2 = t & 1;
    const int mat = h >> 1;
    const int half = h & 1;
    const u16* G = mat ? Bt : A;
    const int rowbase = (mat ? bcol : brow) + half * 128;
    const int k0 = t << 6;
    u16* Ld = &L[bb2][mat][half * 8192 + wid * 512];
    const u16* gsrc = G + (size_t)(rowbase + srow0) * DD + k0 + scol;
    gl_lds16(gsrc, Ld);
    gl_lds16(gsrc + (size_t)64 * DD, Ld + 4096);
  };

  f32x4 acc[8][4];
#pragma unroll
  for (int m = 0; m < 8; ++m)
#pragma unroll
    for (int n = 0; n < 4; ++n) acc[m][n] = zero4();

  bf16x8 af[4][2], bf[4][2];

#pragma unroll
  for (int gi = 0; gi < 5; ++gi) STAGE(gi);
  asm volatile("s_waitcnt vmcnt(2)" ::: "memory");
  BAR();

  for (int kt = 0; kt < NT; ++kt) {
    const int bb = kt & 1;
    const int gb = 4 * kt;
    RDA(bb, 0); RDB(bb, 0);
    STAGE(gb + 5);
    BAR(); LGKM0();
    PRIO1(); MFMA16(0, 0); PRIO0();
    BAR();
    RDB(bb, 1);
    STAGE(gb + 6);
    BAR(); LGKM0();
    PRIO1(); MFMA16(0, 1); PRIO0();
    BAR();
    RDA(bb, 1);
    STAGE(gb + 7);
    BAR(); LGKM0();
    PRIO1(); MFMA16(1, 0); PRIO0();
    BAR();
    STAGE(gb + 8);
    if (kt < NT - 2) {
      asm volatile("s_waitcnt vmcnt(2)" ::: "memory");
    } else {
      asm volatile("s_waitcnt vmcnt(0)" ::: "memory");
    }
    BAR(); LGKM0();
    PRIO1(); MFMA16(1, 1); PRIO0();
    BAR();
  }

#pragma unroll
  for (int m = 0; m < 8; ++m) {
#pragma unroll
    for (int n = 0; n < 4; ++n) {
#pragma unroll
      for (int r = 0; r < 4; ++r) {
        int row = brow + wr * 128 + m * 16 + g * 4 + r;
        int col = bcol + wc * 64 + n * 16 + li;
        float v = acc[m][n][r];
        if (MODE == 0) {
          ((u16*)Cout)[(size_t)row * DD + col] = f2bf(v);
        } else if (MODE == 1) {
          ((u16*)Cout)[((size_t)((row >> 11) << 12) + col) * SS + (row & 2047)] = f2bf(v);
        } else {
          ((float*)Cout)[(size_t)row * DD + col] = v;
        }
      }
    }
  }
}

// ---------------- RoPE in-place on Q and K; Q pre-scaled by 1/sqrt(HD)*log2e ----------------
__global__ __launch_bounds__(256) void k_rope(u16* __restrict__ Q, u16* __restrict__ Kp,
                                              const float* __restrict__ fc,
                                              const float* __restrict__ fs) {
  int idx = blockIdx.x * blockDim.x + threadIdx.x;
  const int n8 = MM * DD / 8;
  const float qsc = idx < n8 ? 0.08838834764831845f * 1.44269504088896340f : 1.0f;
  u16* T = idx < n8 ? Q : Kp;
  int i = idx < n8 ? idx : idx - n8;
  int m = i >> 9;
  int c = (i & 511) * 8;
  int s = m & (SS - 1);
  int i0 = (c & (HDD - 1)) >> 1;
  size_t o = (size_t)m * DD + c;
  ushort8 v = *(ushort8*)(T + o);
  float4v cs = *(const float4v*)(fc + s * 64 + i0);
  float4v sn = *(const float4v*)(fs + s * 64 + i0);
  ushort8 ov;
#pragma unroll
  for (int p = 0; p < 4; ++p) {
    float a = bf2f(v[2 * p]), cc = bf2f(v[2 * p + 1]);
    ov[2 * p]     = f2bf((a * cs[p] - cc * sn[p]) * qsc);
    ov[2 * p + 1] = f2bf((a * sn[p] + cc * cs[p]) * qsc);
  }
  *(ushort8*)(T + o) = ov;
}

// ---------------- flash attention v7: pair-unrolled, cvt_pk, raw v_exp ----------------
// KVBLK=32 dbuf pipeline from v6, with: static buffer indices (2x unroll; tile
// count 2qt+2 is always even), diag-masking only in the peeled last pair,
// v_cvt_pk_bf16_f32 P-packing, raw v_exp_f32 softmax exp.
__global__ __launch_bounds__(256) void k_attn(const u16* __restrict__ Q,
                                              const u16* __restrict__ K,
                                              const u16* __restrict__ VT,
                                              u16* __restrict__ O) {
  __shared__ __align__(16) u16 Kl[2][32 * 128];
  __shared__ __align__(16) u16 Vl[2][128 * 32];
  __shared__ __align__(16) u16 Pl[4][16 * 32];
  const int bh = blockIdx.x;       // fast dim -> all qt-blocks of (b,h) on XCD bh%8
  const int qt = 31 - blockIdx.y;  // heavy blocks dispatch first
  const int b = bh >> 5, h = bh & 31;
  const int tid = threadIdx.x, w = tid >> 6, lane = tid & 63;
  const int g = lane >> 4, li = lane & 15;

  const u16* Qbase = Q + ((size_t)(b * SS + qt * 64 + w * 16 + li)) * DD + h * HDD;
  const u16* Kbase = K + ((size_t)(b * SS)) * DD + h * HDD;
  const u16* Vbase = VT + ((size_t)bh) * HDD * SS;

  bf16x8 qf[4];
#pragma unroll
  for (int ks = 0; ks < 4; ++ks)
    qf[ks] = *(const bf16x8*)(Qbase + ks * 32 + g * 8);

  f32x4 oa[8];
#pragma unroll
  for (int f = 0; f < 8; ++f) oa[f] = zero4();
  float mrun = -1e30f, lrun = 0.f;  // scalar state for q-row = w*16 + li
  const int wli = w * 16 + li;

  // --- staging address precompute (per-lane global sources, wave-uniform LDS dests) ---
  const int krow0 = w * 8 + (lane >> 4);
  const int ksg0 = (lane & 15) ^ (lane >> 4);
  const int ksg1 = (lane & 15) ^ (4 + (lane >> 4));
  const int vdr0 = w * 16 + (lane >> 2);
  const int va0 = (vdr0 * 64 + (lane & 3) * 16) ^ (((vdr0 >> 1) & 7) << 4);
  const int vdr1 = vdr0 + 64;
  const int va1 = (vdr1 * 64 + (lane & 3) * 16) ^ (((vdr1 >> 1) & 7) << 4);

  auto STAGE = [&](int t, int nb) {
    const u16* Kt = Kbase + (size_t)(t * 32) * DD;
    gl_lds16(Kt + (size_t)krow0 * DD + ksg0 * 8, &Kl[nb][(w * 8) * 128]);
    gl_lds16(Kt + (size_t)(krow0 + 4) * DD + ksg1 * 8, &Kl[nb][(w * 8 + 4) * 128]);
    const u16* Vt = Vbase + t * 32;
    gl_lds16(Vt + (size_t)(va0 >> 6) * SS + ((va0 >> 4) & 3) * 8, &Vl[nb][w * 512]);
    gl_lds16(Vt + (size_t)(va1 >> 6) * SS + ((va1 >> 4) & 3) * 8, &Vl[nb][2048 + w * 512]);
  };

  // koff: compile-time 0 (even diag tile), 32 (odd diag tile), -1 (no mask)
  auto TILE = [&](int kt, int cb, int koff) __attribute__((always_inline)) {
    // QK^T (swapped): sc[ktg][r] = S[k = kt*32 + ktg*16 + g*4 + r][q = wli]
    f32x4 sc[2];
    sc[0] = zero4(); sc[1] = zero4();
    PRIO1();
#pragma unroll
    for (int ks = 0; ks < 4; ++ks) {
#pragma unroll
      for (int ktg = 0; ktg < 2; ++ktg) {
        int kr = ktg * 16 + li;
        int off = (kr * 256 + (ks * 32 + g * 8) * 2) ^ ((kr & 7) << 4);
        bf16x8 kf = *(const bf16x8*)((const char*)Kl[cb] + off);
        sc[ktg] = __builtin_amdgcn_mfma_f32_16x16x32_bf16(kf, qf[ks], sc[ktg], 0, 0, 0);
      }
    }
    PRIO0();

    // lane-parallel online softmax (Q pre-scaled into log2 domain)
    float p[8];
    float tmax = -1e30f;
#pragma unroll
    for (int ktg = 0; ktg < 2; ++ktg) {
#pragma unroll
      for (int r = 0; r < 4; ++r) {
        float s = sc[ktg][r];
        if (koff >= 0 && (koff + ktg * 16 + g * 4 + r > wli)) s = -1e30f;
        p[ktg * 4 + r] = s;
        tmax = fmaxf(tmax, s);
      }
    }
    tmax = fmaxf(tmax, __shfl_xor(tmax, 16));
    tmax = fmaxf(tmax, __shfl_xor(tmax, 32));

    if (__all(tmax <= mrun + 8.f)) {  // T13 defer-max
      float su = 0.f;
#pragma unroll
      for (int i = 0; i < 8; ++i) { p[i] = exp2a(p[i] - mrun); su += p[i]; }
      su += __shfl_xor(su, 16);
      su += __shfl_xor(su, 32);
      lrun += su;
    } else {
      float mnew = fmaxf(mrun, tmax);
      float alpha = exp2a(mrun - mnew);
      mrun = mnew;
      float su = 0.f;
#pragma unroll
      for (int i = 0; i < 8; ++i) { p[i] = exp2a(p[i] - mnew); su += p[i]; }
      su += __shfl_xor(su, 16);
      su += __shfl_xor(su, 32);
      lrun = lrun * alpha + su;
      float av[4];
#pragma unroll
      for (int r = 0; r < 4; ++r) av[r] = __shfl(alpha, g * 20 + r);
#pragma unroll
      for (int f = 0; f < 8; ++f)
#pragma unroll
        for (int r = 0; r < 4; ++r) oa[f][r] *= av[r];
    }

    // P -> LDS via packed cvt (per-wave region; cross-row swizzle as in v6)
    {
      char* Pb = (char*)Pl[w];
      const int swz = ((li >> 1) & 7) << 4;
#pragma unroll
      for (int ktg = 0; ktg < 2; ++ktg) {
#pragma unroll
        for (int j = 0; j < 2; ++j) {
          unsigned pk = cvtpk(p[ktg * 4 + 2 * j], p[ktg * 4 + 2 * j + 1]);
          int off = (li * 64 + ktg * 32 + g * 8 + 4 * j) ^ swz;
          *(unsigned*)(Pb + off) = pk;
        }
      }
    }
    asm volatile("s_waitcnt lgkmcnt(0)" ::: "memory");

    // PV: O[16q][128d] += P[16q][32k] * V[32k][128d]
    PRIO1();
    {
      int poff = (li * 64 + g * 16) ^ (((li >> 1) & 7) << 4);
      bf16x8 pfrag = *(const bf16x8*)((const char*)Pl[w] + poff);
#pragma unroll
      for (int f = 0; f < 8; ++f) {
        int dr = f * 16 + li;
        int voff = (dr * 64 + g * 16) ^ (((dr >> 1) & 7) << 4);
        bf16x8 vf = *(const bf16x8*)((const char*)Vl[cb] + voff);
        oa[f] = __builtin_amdgcn_mfma_f32_16x16x32_bf16(pfrag, vf, oa[f], 0, 0, 0);
      }
    }
    PRIO0();

    asm volatile("s_waitcnt vmcnt(0)" ::: "memory");  // next tile's DMA landed
    __syncthreads();                                  // all waves done with buf cb
  };

  STAGE(0, 0);
  asm volatile("s_waitcnt vmcnt(0)" ::: "memory");
  __syncthreads();

  // unmasked pairs (static buffers, no diag predicate)
  for (int i = 0; i < qt; ++i) {
    STAGE(2 * i + 1, 1);
    TILE(2 * i, 0, -1);
    STAGE(2 * i + 2, 0);
    TILE(2 * i + 1, 1, -1);
  }
  // final (diagonal) pair: masked, no further staging after the odd tile
  STAGE(2 * qt + 1, 1);
  TILE(2 * qt, 0, 0);
  TILE(2 * qt + 1, 1, 32);

  // epilogue: O rows q = g*4 + r; fetch l from the lane owning that q
  float lv[4];
#pragma unroll
  for (int r = 0; r < 4; ++r) lv[r] = __shfl(lrun, g * 20 + r);
  u16* Ob = O + ((size_t)(b * SS + qt * 64 + w * 16 + g * 4)) * DD + h * HDD;
#pragma unroll
  for (int r = 0; r < 4; ++r) {
    float inv = 1.f / lv[r];
#pragma unroll
    for (int f = 0; f < 8; ++f)
      Ob[(size_t)r * DD + f * 16 + li] = f2bf(oa[f][r] * inv);
  }
}

// ---------------- host ----------------
extern "C" void kernel_launch(void* const* d_in, const int* in_sizes, int n_in,
                              void* d_out, int out_size, void* d_ws, size_t ws_size,
                              hipStream_t stream) {
  (void)in_sizes; (void)n_in; (void)out_size; (void)ws_size;
  const float* x    = (const float*)d_in[0];
  const float* Wq   = (const float*)d_in[1];
  const float* Wk   = (const float*)d_in[2];
  const float* Wv   = (const float*)d_in[3];
  const float* Wo   = (const float*)d_in[4];
  const float* fcos = (const float*)d_in[5];
  const float* fsin = (const float*)d_in[6];

  u16* ws = (u16*)d_ws;
  const size_t MAT = (size_t)4096 * 4096;
  u16* xb    = ws + 0 * MAT;
  u16* wqt   = ws + 1 * MAT;
  u16* wkt   = ws + 2 * MAT;
  u16* wvt   = ws + 3 * MAT;
  u16* wot   = ws + 4 * MAT;
  u16* Qb    = ws + 5 * MAT;
  u16* Kb    = ws + 6 * MAT;
  u16* VTb   = ws + 7 * MAT;
  u16* attnb = ws + 8 * MAT;

  k_cvt<<<dim3(8192), dim3(256), 0, stream>>>(x, xb, (int)(MAT / 8));
  k_wt<<<dim3(64, 64, 4), dim3(64, 4), 0, stream>>>(Wq, Wk, Wv, Wo, wqt);
  k_gemm<0><<<dim3(256), dim3(512), 0, stream>>>(xb, wqt, (void*)Qb);
  k_gemm<0><<<dim3(256), dim3(512), 0, stream>>>(xb, wkt, (void*)Kb);
  k_gemm<1><<<dim3(256), dim3(512), 0, stream>>>(xb, wvt, (void*)VTb);
  k_rope<<<dim3(16384), dim3(256), 0, stream>>>(Qb, Kb, fcos, fsin);
  k_attn<<<dim3(64, 32), dim3(256), 0, stream>>>(Qb, Kb, VTb, attnb);
  k_gemm<2><<<dim3(256), dim3(512), 0, stream>>>(attnb, wot, d_out);
}